// Round 1
// baseline (482.266 us; speedup 1.0000x reference)
//
#include <hip/hip_runtime.h>
#include <hip/hip_bf16.h>

// Problem constants
#define BB   128
#define NN   196
#define MM   (BB*NN)      // 25088
#define ENC  2048
#define ATT  512
#define DEC  512

using f32x4 = __attribute__((ext_vector_type(4))) float;
using s16x8 = __attribute__((ext_vector_type(8))) short;

__device__ __forceinline__ short f2bf(float f) {
    union { __hip_bfloat16 h; short s; } u;
    u.h = __float2bfloat16(f);
    return u.s;
}

// ---------------------------------------------------------------------------
// k0a: transpose+convert W_enc [2048][512] f32 -> Wt [512][2048] bf16
// ---------------------------------------------------------------------------
__global__ void transpose_convert_kernel(const float* __restrict__ W,
                                         unsigned short* __restrict__ Wt) {
    __shared__ float tile[32][33];
    const int a0 = blockIdx.x * 32;   // 16 blocks
    const int k0 = blockIdx.y * 32;   // 64 blocks
    const int tx = threadIdx.x & 31, ty = threadIdx.x >> 5;  // 32 x 8
    #pragma unroll
    for (int i = 0; i < 32; i += 8)
        tile[ty + i][tx] = W[(size_t)(k0 + ty + i) * ATT + a0 + tx];
    __syncthreads();
    #pragma unroll
    for (int i = 0; i < 32; i += 8) {
        union { __hip_bfloat16 h; unsigned short u; } v;
        v.h = __float2bfloat16(tile[tx][ty + i]);
        Wt[(size_t)(a0 + ty + i) * ENC + k0 + tx] = v.u;
    }
}

// ---------------------------------------------------------------------------
// k0b: att2[b][a] = dec[b] @ W_dec[:,a] + b_dec[a] + b_enc[a]
// ---------------------------------------------------------------------------
__global__ void att2_kernel(const float* __restrict__ dec,
                            const float* __restrict__ Wd,
                            const float* __restrict__ bd,
                            const float* __restrict__ benc,
                            float* __restrict__ att2) {
    const int b = blockIdx.x;     // 128
    const int t = threadIdx.x;    // 256
    __shared__ float sdec[DEC];
    sdec[t]       = dec[b * DEC + t];
    sdec[t + 256] = dec[b * DEC + t + 256];
    __syncthreads();
    float acc0 = bd[t] + benc[t];
    float acc1 = bd[t + 256] + benc[t + 256];
    #pragma unroll 8
    for (int k = 0; k < DEC; ++k) {
        float d = sdec[k];
        acc0 += d * Wd[k * ATT + t];
        acc1 += d * Wd[k * ATT + t + 256];
    }
    att2[b * ATT + t]       = acc0;
    att2[b * ATT + t + 256] = acc1;
}

// ---------------------------------------------------------------------------
// k1: fused GEMM + bias + relu + dot(W_full) -> e_part[2][MM]
//   M_tile=64, A_tile=256, BK=32, 256 threads (4 waves), wave tile 64x64.
//   A (encoder, fp32) staged via global_load_lds w/ XOR chunk swizzle,
//   converted to bf16 in-register. B = Wt (bf16, [a][k]) staged identity.
// ---------------------------------------------------------------------------
__global__ __launch_bounds__(256, 3)
void gemm_e_kernel(const float* __restrict__ enc,
                   const unsigned short* __restrict__ Wt,
                   const float* __restrict__ att2,
                   const float* __restrict__ Wf,
                   float* __restrict__ e_part) {
    __shared__ float sA[64 * 32];            // 8 KB, swizzled 16B-chunk layout
    __shared__ unsigned short sB[256 * 32];  // 16 KB, [a_local][32k], 64 B rows
    __shared__ float e_sm[64];

    const int t    = threadIdx.x;
    const int lane = t & 63;
    const int w    = t >> 6;              // wave 0..3
    const int aBlk  = blockIdx.x;         // 0..1 (fastest -> twin M-tiles adjacent)
    const int mBase = blockIdx.y * 64;    // 392 tiles
    const int aBase = aBlk * 256;

    // --- staging global base addresses (per-thread) ---
    const char* gA[2];
    #pragma unroll
    for (int i = 0; i < 2; ++i) {
        int s = i * 256 + t;
        int row = s >> 3;                    // 0..63
        int sc  = s & 7;                     // LDS chunk pos within row
        int ck  = sc ^ (row & 7);            // swizzle: global chunk held here
        gA[i] = (const char*)enc + ((size_t)(mBase + row) * ENC + (size_t)ck * 4) * 4;
    }
    const char* gB[4];
    #pragma unroll
    for (int i = 0; i < 4; ++i) {
        int s = i * 256 + t;
        int arow = s >> 2;                   // 0..255
        int ck   = s & 3;
        gB[i] = (const char*)Wt + ((size_t)(aBase + arow) * ENC + (size_t)ck * 8) * 2;
    }
    char* lA = (char*)sA;
    char* lB = (char*)sB;

    // --- fragment read offsets (k-invariant) ---
    const int r = lane & 15, q = lane >> 4;
    int offA[4][2];
    #pragma unroll
    for (int mi = 0; mi < 4; ++mi) {
        int lrow = mi * 16 + r;
        offA[mi][0] = lrow * 128 + (((2 * q)     ^ (lrow & 7)) * 16);
        offA[mi][1] = lrow * 128 + (((2 * q + 1) ^ (lrow & 7)) * 16);
    }
    int offB[4];
    #pragma unroll
    for (int ni = 0; ni < 4; ++ni) {
        int col = w * 64 + ni * 16 + r;
        offB[ni] = col * 64 + q * 16;
    }

    f32x4 acc[4][4] = {};

    for (int ks = 0; ks < ENC / 32; ++ks) {
        // stage A (2x16B/thread) + B (4x16B/thread) into LDS
        #pragma unroll
        for (int i = 0; i < 2; ++i)
            __builtin_amdgcn_global_load_lds(
                (const __attribute__((address_space(1))) void*)(gA[i] + (size_t)ks * 128),
                (__attribute__((address_space(3))) void*)(lA + (i * 256 + w * 64) * 16),
                16, 0, 0);
        #pragma unroll
        for (int i = 0; i < 4; ++i)
            __builtin_amdgcn_global_load_lds(
                (const __attribute__((address_space(1))) void*)(gB[i] + (size_t)ks * 64),
                (__attribute__((address_space(3))) void*)(lB + (i * 256 + w * 64) * 16),
                16, 0, 0);
        __syncthreads();   // compiler inserts vmcnt(0) drain before barrier

        s16x8 af[4], bf[4];
        #pragma unroll
        for (int mi = 0; mi < 4; ++mi) {
            f32x4 f0 = *(const f32x4*)((const char*)sA + offA[mi][0]);
            f32x4 f1 = *(const f32x4*)((const char*)sA + offA[mi][1]);
            s16x8 a;
            a[0] = f2bf(f0[0]); a[1] = f2bf(f0[1]); a[2] = f2bf(f0[2]); a[3] = f2bf(f0[3]);
            a[4] = f2bf(f1[0]); a[5] = f2bf(f1[1]); a[6] = f2bf(f1[2]); a[7] = f2bf(f1[3]);
            af[mi] = a;
        }
        #pragma unroll
        for (int ni = 0; ni < 4; ++ni)
            bf[ni] = *(const s16x8*)((const char*)sB + offB[ni]);

        #pragma unroll
        for (int mi = 0; mi < 4; ++mi)
            #pragma unroll
            for (int ni = 0; ni < 4; ++ni)
                acc[mi][ni] = __builtin_amdgcn_mfma_f32_16x16x32_bf16(
                    af[mi], bf[ni], acc[mi][ni], 0, 0, 0);
        __syncthreads();   // compute done before next stage overwrites LDS
    }

    // --- epilogue: e contribution = sum_a relu(att1 + att2) * Wf ---
    if (t < 64) e_sm[t] = 0.f;
    __syncthreads();

    float wfv[4];
    #pragma unroll
    for (int ni = 0; ni < 4; ++ni)
        wfv[ni] = Wf[aBase + w * 64 + ni * 16 + r];

    #pragma unroll
    for (int mi = 0; mi < 4; ++mi) {
        #pragma unroll
        for (int reg = 0; reg < 4; ++reg) {
            int lrow = mi * 16 + q * 4 + reg;       // C/D: row=(lane>>4)*4+reg
            int gm = mBase + lrow;
            int b = gm / NN;
            const float* a2 = att2 + b * ATT + aBase + w * 64;
            float rs = 0.f;
            #pragma unroll
            for (int ni = 0; ni < 4; ++ni) {
                float v = acc[mi][ni][reg] + a2[ni * 16 + r];  // col = lane&15
                rs += fmaxf(v, 0.f) * wfv[ni];
            }
            atomicAdd(&e_sm[lrow], rs);
        }
    }
    __syncthreads();
    if (t < 64)
        e_part[(size_t)aBlk * MM + mBase + t] = e_sm[t];
}

// ---------------------------------------------------------------------------
// k2: softmax over N per batch, then awe[b][c] = sum_n enc[b][n][c]*alpha[n]
// ---------------------------------------------------------------------------
__global__ void softmax_awe_kernel(const float* __restrict__ enc,
                                   const float* __restrict__ e_part,
                                   const float* __restrict__ b_full,
                                   float* __restrict__ out) {
    const int b = blockIdx.x;       // 128
    const int chunk = blockIdx.y;   // 8
    const int t = threadIdx.x;      // 256
    __shared__ float sm[256];
    __shared__ float alpha_sm[NN];

    float v = -3.0e38f;
    if (t < NN) {
        int gm = b * NN + t;
        v = e_part[gm] + e_part[MM + gm] + b_full[0];
    }
    sm[t] = v;
    __syncthreads();
    for (int s = 128; s > 0; s >>= 1) {
        if (t < s) sm[t] = fmaxf(sm[t], sm[t + s]);
        __syncthreads();
    }
    float mx = sm[0];
    __syncthreads();
    float ex = (t < NN) ? __expf(v - mx) : 0.f;
    sm[t] = ex;
    __syncthreads();
    for (int s = 128; s > 0; s >>= 1) {
        if (t < s) sm[t] += sm[t + s];
        __syncthreads();
    }
    float inv = 1.0f / sm[0];
    if (t < NN) alpha_sm[t] = ex * inv;
    __syncthreads();

    if (chunk == 0 && t < NN)
        out[BB * ENC + b * NN + t] = ex * inv;   // alpha output

    const int col = chunk * 256 + t;
    const float* ep = enc + (size_t)b * NN * ENC + col;
    float acc = 0.f;
    #pragma unroll 4
    for (int n = 0; n < NN; n += 4) {
        acc += ep[(size_t)n * ENC]       * alpha_sm[n]
             + ep[(size_t)(n + 1) * ENC] * alpha_sm[n + 1]
             + ep[(size_t)(n + 2) * ENC] * alpha_sm[n + 2]
             + ep[(size_t)(n + 3) * ENC] * alpha_sm[n + 3];
    }
    out[b * ENC + col] = acc;
}

// ---------------------------------------------------------------------------
extern "C" void kernel_launch(void* const* d_in, const int* in_sizes, int n_in,
                              void* d_out, int out_size, void* d_ws, size_t ws_size,
                              hipStream_t stream) {
    const float* enc    = (const float*)d_in[0];   // [128,196,2048]
    const float* dec    = (const float*)d_in[1];   // [128,512]
    const float* W_enc  = (const float*)d_in[2];   // [2048,512]
    const float* b_enc  = (const float*)d_in[3];   // [512]
    const float* W_dec  = (const float*)d_in[4];   // [512,512]
    const float* b_dec  = (const float*)d_in[5];   // [512]
    const float* W_full = (const float*)d_in[6];   // [512]
    const float* b_full = (const float*)d_in[7];   // [1]
    float* out = (float*)d_out;                    // [128*2048 awe | 128*196 alpha]

    // workspace layout
    char* ws = (char*)d_ws;
    unsigned short* Wt = (unsigned short*)ws;                       // 2 MB
    float* att2   = (float*)(ws + (size_t)ENC * ATT * 2);           // 256 KB
    float* e_part = (float*)(ws + (size_t)ENC * ATT * 2 + BB * ATT * 4); // 2*25088*4

    transpose_convert_kernel<<<dim3(ATT / 32, ENC / 32), 256, 0, stream>>>(W_enc, Wt);
    att2_kernel<<<BB, 256, 0, stream>>>(dec, W_dec, b_dec, b_enc, att2);
    gemm_e_kernel<<<dim3(2, MM / 64), 256, 0, stream>>>(enc, Wt, att2, W_full, e_part);
    softmax_awe_kernel<<<dim3(BB, 8), 256, 0, stream>>>(enc, e_part, b_full, out);
}